// Round 1
// baseline (574.347 us; speedup 1.0000x reference)
//
#include <hip/hip_runtime.h>
#include <hip/hip_bf16.h>
#include <math.h>

#define SS   16
#define NN   1024
#define RR   4
#define CINC 128
#define COUTC 128
#define RP1  5
#define EPSF 1e-7f

typedef __bf16 bf16x8 __attribute__((ext_vector_type(8)));
typedef __bf16 bf16x4 __attribute__((ext_vector_type(4)));
typedef float  f32x4  __attribute__((ext_vector_type(4)));

// Workspace layout:
//   Yt : bf16 [S][R][COUT][N]  = 16 MiB   (Y_c = X_s @ W_c, b-major for B-frag loads)
//   Z  : f32  [S][N][COUT]     =  8 MiB
//   xb : bf16 [S][N][CIN]      =  4 MiB   (x pre-converted once)
//   Wt : bf16 [5][COUT][CIN]   =  160 KiB (transposed weight, ch 4 = theta)
#define YT_BYTES ((size_t)SS * RR * COUTC * NN * 2)
#define Z_BYTES  ((size_t)SS * NN * COUTC * 4)
#define XB_BYTES ((size_t)SS * NN * CINC * 2)

// ---------------------------------------------------------------------------
// Kernel 0: one-shot layout conversion.
//   xb[s][j][a] = bf16(x[s][j][a])            (vectorized 8-wide)
//   Wt[ch][b][a] = bf16(weight[a][b][ch])  ch<4 ;  Wt[4][b][a] = bf16(theta[a][b])
// ---------------------------------------------------------------------------
__global__ __launch_bounds__(256) void convert_kernel(
    const float* __restrict__ x, const float* __restrict__ weight,
    const float* __restrict__ theta, __bf16* __restrict__ xb,
    __bf16* __restrict__ Wt)
{
    const int tid = blockIdx.x * 256 + threadIdx.x;
    const int XT = SS * NN * CINC / 8;          // 262144 threads for xb
    if (tid < XT) {
        f32x4 a = *(const f32x4*)(x + (size_t)tid * 8);
        f32x4 b = *(const f32x4*)(x + (size_t)tid * 8 + 4);
        bf16x8 o;
        o[0] = (__bf16)a.x; o[1] = (__bf16)a.y; o[2] = (__bf16)a.z; o[3] = (__bf16)a.w;
        o[4] = (__bf16)b.x; o[5] = (__bf16)b.y; o[6] = (__bf16)b.z; o[7] = (__bf16)b.w;
        *(bf16x8*)(xb + (size_t)tid * 8) = o;
    } else {
        const int u = tid - XT;                 // 5*128*128 = 81920 Wt elems
        if (u < 5 * COUTC * CINC) {
            const int ch = u >> 14;
            const int b  = (u >> 7) & 127;
            const int a  = u & 127;
            const float v = (ch < 4) ? weight[((size_t)a * COUTC + b) * RR + ch]
                                     : theta[(size_t)a * COUTC + b];
            Wt[u] = (__bf16)v;
        }
    }
}

// ---------------------------------------------------------------------------
// Kernel 1: Yt[s][c][b][j] = bf16( sum_a xb[s][j][a] * Wt[c][b][a] )   (c<4)
//           Z [s][j][b]    =       sum_a xb[s][j][a] * Wt[4][b][a]     (ch==4)
// LDS-free, barrier-free: fragments loaded straight from L2.
// grid = 1280 blocks (XCD-chunked so writes land in the reading XCD's L2), 256 thr
// ---------------------------------------------------------------------------
__global__ __launch_bounds__(256) void prep_kernel(
    const __bf16* __restrict__ xb, const __bf16* __restrict__ Wt,
    __bf16* __restrict__ Yt, float* __restrict__ Z)
{
    const int bx   = blockIdx.x;
    const int idx  = bx >> 3;                  // 0..159 per XCD
    const int s    = (bx & 7) * 2 + (idx & 1); // XCD k owns s in {2k, 2k+1}
    const int rest = idx >> 1;                 // 0..79  = 5 ch * 16 it
    const int ch   = rest % 5;
    const int it   = rest / 5;

    const int t = threadIdx.x, lane = t & 63, w = t >> 6;
    const int m16 = lane & 15, quad = lane >> 4;

    // A-frag: this lane's token row (16B loads; 16 rows x 4 quads = full 64B lines)
    const __bf16* xrow = xb + ((size_t)s * NN + it * 64 + w * 16 + m16) * CINC;
    // B-frag: weight row b = bs*16+m16
    const __bf16* wch  = Wt + (size_t)ch * COUTC * CINC + (size_t)m16 * CINC;

    f32x4 acc[8];
#pragma unroll
    for (int i = 0; i < 8; ++i) acc[i] = (f32x4){0.f, 0.f, 0.f, 0.f};

#pragma unroll
    for (int k0 = 0; k0 < CINC; k0 += 32) {
        const bf16x8 af = *(const bf16x8*)(xrow + k0 + quad * 8);
#pragma unroll
        for (int bs = 0; bs < 8; ++bs) {
            const bf16x8 bv = *(const bf16x8*)(wch + (size_t)bs * 16 * CINC + k0 + quad * 8);
            acc[bs] = __builtin_amdgcn_mfma_f32_16x16x32_bf16(af, bv, acc[bs], 0, 0, 0);
        }
    }

    const int j0 = it * 64 + w * 16 + quad * 4;    // token row base (C rows)
    if (ch < 4) {
#pragma unroll
        for (int bs = 0; bs < 8; ++bs) {
            const int b = bs * 16 + m16;
            __bf16* p = Yt + (((size_t)(s * 4 + ch) * COUTC + b) * NN + j0);
            bf16x4 v; v[0] = (__bf16)acc[bs][0]; v[1] = (__bf16)acc[bs][1];
                      v[2] = (__bf16)acc[bs][2]; v[3] = (__bf16)acc[bs][3];
            *(bf16x4*)p = v;
        }
    } else {
#pragma unroll
        for (int bs = 0; bs < 8; ++bs) {
            const int b = bs * 16 + m16;
#pragma unroll
            for (int r = 0; r < 4; ++r)
                Z[((size_t)s * NN + j0 + r) * COUTC + b] = acc[bs][r];
        }
    }
}

// ---------------------------------------------------------------------------
// Kernel 2: out[s,i,b] = tanh( Z[s,i,b] + sum_c norm[s,i,c] * sum_j Ar[s,i,j,c]*Y_c[j,b] )
// grid = 512 blocks, 256 thr, 2 blocks/CU. XCD-chunked: XCD k owns s in {2k,2k+1}
// so the 2 MiB Yt working set per XCD is L2-resident (was 16 MiB -> L3).
// Double-buffered lA: ONE __syncthreads per kk step (was two).
// ---------------------------------------------------------------------------
__global__ __launch_bounds__(256, 2) void main_kernel(
    const float* __restrict__ A, const __bf16* __restrict__ Yt,
    const float* __restrict__ Z, float* __restrict__ out)
{
    const int bx  = blockIdx.x;
    const int idx = bx >> 3;                   // 0..63 per XCD
    const int s   = (bx & 7) * 2 + (idx >> 5); // matches prep's placement
    const int i0  = (idx & 31) * 32;

    __shared__ __bf16 lA[2][4][32][40];        // double-buffered [c][i][j], stride 40
    __shared__ float  lnorm[4][32];

    const int t = threadIdx.x;
    const int lane = t & 63, w = t >> 6;
    const int m16 = lane & 15, quad = lane >> 4;

    const int irow = t >> 3;                   // staging row 0..31
    const int q    = t & 7;                    // staging j-group (4 j's each)

    const float* Ap = A + ((size_t)(s * NN + i0 + irow) * NN) * RP1 + q * 20;

    float rs[4] = {0.f, 0.f, 0.f, 0.f};
    f32x4 acc[4][2][2];
#pragma unroll
    for (int c = 0; c < 4; ++c)
#pragma unroll
        for (int is = 0; is < 2; ++is)
#pragma unroll
            for (int bs = 0; bs < 2; ++bs) acc[c][is][bs] = (f32x4){0.f, 0.f, 0.f, 0.f};

    const __bf16* Ys = Yt + (size_t)s * 4 * COUTC * NN;

    // prologue A prefetch (5 aligned dwordx4 = 4 j's x 5 channels)
    f32x4 ld[5];
#pragma unroll
    for (int u = 0; u < 5; ++u) ld[u] = __builtin_nontemporal_load((const f32x4*)Ap + u);

    for (int kk = 0; kk < 32; ++kk) {
        // B-fragments for this step (L2-resident Yt)
        bf16x8 bf[4][2];
        const __bf16* yp = Ys + kk * 32 + quad * 8;
#pragma unroll
        for (int c = 0; c < 4; ++c)
#pragma unroll
            for (int bs = 0; bs < 2; ++bs)
                bf[c][bs] = *(const bf16x8*)(yp + (size_t)(c * COUTC + w * 32 + bs * 16 + m16) * NN);

        const int ib = kk & 1;
        {   // de-interleave channels, convert, stage into buffer ib; fp32 row-sums
            const float v0[4] = {ld[0].x, ld[1].y, ld[2].z, ld[3].w};
            const float v1[4] = {ld[0].y, ld[1].z, ld[2].w, ld[4].x};
            const float v2[4] = {ld[0].z, ld[1].w, ld[3].x, ld[4].y};
            const float v3[4] = {ld[0].w, ld[2].x, ld[3].y, ld[4].z};
            const float* vv[4] = {v0, v1, v2, v3};
#pragma unroll
            for (int c = 0; c < 4; ++c) {
                const float* v = vv[c];
                rs[c] += v[0] + v[1] + v[2] + v[3];
                bf16x4 pk; pk[0] = (__bf16)v[0]; pk[1] = (__bf16)v[1];
                           pk[2] = (__bf16)v[2]; pk[3] = (__bf16)v[3];
                *(bf16x4*)&lA[ib][c][irow][q * 4] = pk;
            }
        }
        __syncthreads();   // staged tile visible; prior-buffer reads are all pre-barrier

        if (kk < 31) {     // prefetch next A step AFTER the barrier drain -> overlaps MFMA
            Ap += 160;
#pragma unroll
            for (int u = 0; u < 5; ++u) ld[u] = __builtin_nontemporal_load((const f32x4*)Ap + u);
        }

#pragma unroll
        for (int c = 0; c < 4; ++c) {
            const bf16x8 af0 = *(const bf16x8*)&lA[ib][c][m16][quad * 8];
            const bf16x8 af1 = *(const bf16x8*)&lA[ib][c][16 + m16][quad * 8];
            acc[c][0][0] = __builtin_amdgcn_mfma_f32_16x16x32_bf16(af0, bf[c][0], acc[c][0][0], 0, 0, 0);
            acc[c][0][1] = __builtin_amdgcn_mfma_f32_16x16x32_bf16(af0, bf[c][1], acc[c][0][1], 0, 0, 0);
            acc[c][1][0] = __builtin_amdgcn_mfma_f32_16x16x32_bf16(af1, bf[c][0], acc[c][1][0], 0, 0, 0);
            acc[c][1][1] = __builtin_amdgcn_mfma_f32_16x16x32_bf16(af1, bf[c][1], acc[c][1][1], 0, 0, 0);
        }
    }

    // row-sums -> norms (8 staging lanes per row, xor-shuffle reduce)
#pragma unroll
    for (int c = 0; c < 4; ++c) {
        float v = rs[c];
        v += __shfl_xor(v, 1);
        v += __shfl_xor(v, 2);
        v += __shfl_xor(v, 4);
        if (q == 0) lnorm[c][irow] = 1.0f / (v + EPSF);
    }
    __syncthreads();

    // epilogue: combine c's with norms, add Z, tanh, store
#pragma unroll
    for (int is = 0; is < 2; ++is) {
        f32x4 nv[4];
#pragma unroll
        for (int c = 0; c < 4; ++c) nv[c] = *(const f32x4*)&lnorm[c][is * 16 + quad * 4];
        const int row0 = i0 + is * 16 + quad * 4;
#pragma unroll
        for (int bs = 0; bs < 2; ++bs) {
            const int b = w * 32 + bs * 16 + m16;
#pragma unroll
            for (int r = 0; r < 4; ++r) {
                float v = acc[0][is][bs][r] * nv[0][r]
                        + acc[1][is][bs][r] * nv[1][r]
                        + acc[2][is][bs][r] * nv[2][r]
                        + acc[3][is][bs][r] * nv[3][r];
                const size_t idxo = ((size_t)s * NN + row0 + r) * COUTC + b;
                out[idxo] = tanhf(v + Z[idxo]);
            }
        }
    }
}

extern "C" void kernel_launch(void* const* d_in, const int* in_sizes, int n_in,
                              void* d_out, int out_size, void* d_ws, size_t ws_size,
                              hipStream_t stream)
{
    const float* A      = (const float*)d_in[0];
    const float* x      = (const float*)d_in[1];
    const float* weight = (const float*)d_in[2];
    const float* theta  = (const float*)d_in[3];
    float* out = (float*)d_out;

    __bf16* Yt = (__bf16*)d_ws;
    float*  Z  = (float*)((char*)d_ws + YT_BYTES);
    __bf16* xb = (__bf16*)((char*)d_ws + YT_BYTES + Z_BYTES);
    __bf16* Wt = (__bf16*)((char*)d_ws + YT_BYTES + Z_BYTES + XB_BYTES);

    // 262144 xb-threads + 81920 Wt-threads = 344064 = 1344 * 256
    convert_kernel<<<dim3(1344), dim3(256), 0, stream>>>(x, weight, theta, xb, Wt);
    prep_kernel<<<dim3(SS * 5 * 16), dim3(256), 0, stream>>>(xb, Wt, Yt, Z);
    main_kernel<<<dim3(SS * 32), dim3(256), 0, stream>>>(A, Yt, Z, out);
}

// Round 3
// 568.912 us; speedup vs baseline: 1.0096x; 1.0096x over previous
//
#include <hip/hip_runtime.h>
#include <hip/hip_bf16.h>
#include <math.h>

#define SS   16
#define NN   1024
#define RR   4
#define CINC 128
#define COUTC 128
#define RP1  5
#define EPSF 1e-7f

typedef __bf16 bf16x8 __attribute__((ext_vector_type(8)));
typedef __bf16 bf16x4 __attribute__((ext_vector_type(4)));
typedef float  f32x4  __attribute__((ext_vector_type(4)));

// Workspace layout:
//   Yt : bf16 [S][R][COUT][N]  = 16 MiB   (Y_c = X_s @ W_c, b-major for B-frag loads)
//   Wt : bf16 [5][COUT][CIN]   = 160 KiB  (transposed weight, ch 4 = theta)
#define YT_BYTES ((size_t)SS * RR * COUTC * NN * 2)

// ---------------------------------------------------------------------------
// Kernel 0: tiny one-shot weight transpose+convert (81920 elems, exact grid).
//   Wt[ch][b][a] = bf16(weight[a][b][ch])  ch<4 ;  Wt[4][b][a] = bf16(theta[a][b])
// ---------------------------------------------------------------------------
__global__ __launch_bounds__(256) void convert_kernel(
    const float* __restrict__ weight, const float* __restrict__ theta,
    __bf16* __restrict__ Wt)
{
    const int u  = blockIdx.x * 256 + threadIdx.x;   // 5*128*128 = 81920 = 320*256
    const int ch = u >> 14;
    const int b  = (u >> 7) & 127;
    const int a  = u & 127;
    const float v = (ch < 4) ? weight[((size_t)a * COUTC + b) * RR + ch]
                             : theta[(size_t)a * COUTC + b];
    Wt[u] = (__bf16)v;   // consecutive a -> coalesced bf16 stores
}

// ---------------------------------------------------------------------------
// Kernel 1: Yt[s][c][b][j] = bf16( sum_a x[s][j][a] * Wt[c][b][a] )   c = 0..3
// LDS-free, barrier-free; x read fp32 and converted in-register (same rounding
// path as before). grid = 16 s * 4 ch * 16 it = 1024 blocks, XCD-chunked.
// ---------------------------------------------------------------------------
__global__ __launch_bounds__(256) void prep_kernel(
    const float* __restrict__ x, const __bf16* __restrict__ Wt,
    __bf16* __restrict__ Yt)
{
    const int bx   = blockIdx.x;
    const int idx  = bx >> 3;                  // 0..127 per XCD
    const int s    = (bx & 7) * 2 + (idx & 1); // XCD k owns s in {2k, 2k+1}
    const int rest = idx >> 1;                 // 0..63 = 4 ch * 16 it
    const int ch   = rest & 3;
    const int it   = rest >> 2;

    const int t = threadIdx.x, lane = t & 63, w = t >> 6;
    const int m16 = lane & 15, quad = lane >> 4;

    const float*  xrow = x  + ((size_t)s * NN + it * 64 + w * 16 + m16) * CINC;
    const __bf16* wch  = Wt + (size_t)ch * COUTC * CINC + (size_t)m16 * CINC;

    f32x4 acc[8];
#pragma unroll
    for (int i = 0; i < 8; ++i) acc[i] = (f32x4){0.f, 0.f, 0.f, 0.f};

#pragma unroll
    for (int k0 = 0; k0 < CINC; k0 += 32) {
        const f32x4 x0 = *(const f32x4*)(xrow + k0 + quad * 8);
        const f32x4 x1 = *(const f32x4*)(xrow + k0 + quad * 8 + 4);
        bf16x8 af;
        af[0] = (__bf16)x0.x; af[1] = (__bf16)x0.y; af[2] = (__bf16)x0.z; af[3] = (__bf16)x0.w;
        af[4] = (__bf16)x1.x; af[5] = (__bf16)x1.y; af[6] = (__bf16)x1.z; af[7] = (__bf16)x1.w;
#pragma unroll
        for (int bs = 0; bs < 8; ++bs) {
            const bf16x8 bv = *(const bf16x8*)(wch + (size_t)bs * 16 * CINC + k0 + quad * 8);
            acc[bs] = __builtin_amdgcn_mfma_f32_16x16x32_bf16(af, bv, acc[bs], 0, 0, 0);
        }
    }

    const int j0 = it * 64 + w * 16 + quad * 4;    // token row base (C rows)
#pragma unroll
    for (int bs = 0; bs < 8; ++bs) {
        const int b = bs * 16 + m16;
        __bf16* p = Yt + (((size_t)(s * 4 + ch) * COUTC + b) * NN + j0);
        bf16x4 v; v[0] = (__bf16)acc[bs][0]; v[1] = (__bf16)acc[bs][1];
                  v[2] = (__bf16)acc[bs][2]; v[3] = (__bf16)acc[bs][3];
        *(bf16x4*)p = v;
    }
}

// ---------------------------------------------------------------------------
// Kernel 2: out[s,i,b] = tanh( (x@theta)[i,b] + sum_c norm[s,i,c] * (Ar_c @ Y_c)[i,b] )
// grid = 512 blocks, 256 thr, 2 blocks/CU, XCD-chunked to match prep.
// Z is computed in-kernel (16 MFMAs from L2-resident x and Wt[4]) -> no Z buffer.
// ---------------------------------------------------------------------------
__global__ __launch_bounds__(256, 2) void main_kernel(
    const float* __restrict__ A, const __bf16* __restrict__ Yt,
    const float* __restrict__ x, const __bf16* __restrict__ Wt,
    float* __restrict__ out)
{
    const int bx  = blockIdx.x;
    const int idx = bx >> 3;                   // 0..63 per XCD
    const int s   = (bx & 7) * 2 + (idx >> 5); // matches prep's placement
    const int i0  = (idx & 31) * 32;

    __shared__ __bf16 lA[2][4][32][40];        // double-buffered [c][i][j], stride 40
    __shared__ float  lnorm[4][32];

    const int t = threadIdx.x;
    const int lane = t & 63, w = t >> 6;
    const int m16 = lane & 15, quad = lane >> 4;

    const int irow = t >> 3;                   // staging row 0..31
    const int q    = t & 7;                    // staging j-group (4 j's each)

    const float* Ap = A + ((size_t)(s * NN + i0 + irow) * NN) * RP1 + q * 20;

    // prologue A prefetch (5 aligned dwordx4 = 4 j's x 5 channels)
    f32x4 ld[5];
#pragma unroll
    for (int u = 0; u < 5; ++u) ld[u] = __builtin_nontemporal_load((const f32x4*)Ap + u);

    // ---- Z-phase: accz[is][bs] = (x @ theta) tile, theta = Wt[4] (bf16) ----
    f32x4 accz[2][2];
#pragma unroll
    for (int is = 0; is < 2; ++is)
#pragma unroll
        for (int bs = 0; bs < 2; ++bs) accz[is][bs] = (f32x4){0.f, 0.f, 0.f, 0.f};
    {
        const __bf16* th = Wt + (size_t)4 * COUTC * CINC;
#pragma unroll
        for (int k0 = 0; k0 < CINC; k0 += 32) {
            bf16x8 tf[2];
#pragma unroll
            for (int bs = 0; bs < 2; ++bs)
                tf[bs] = *(const bf16x8*)(th + (size_t)(w * 32 + bs * 16 + m16) * CINC + k0 + quad * 8);
#pragma unroll
            for (int is = 0; is < 2; ++is) {
                const float* xr = x + ((size_t)s * NN + i0 + is * 16 + m16) * CINC + k0 + quad * 8;
                const f32x4 x0 = *(const f32x4*)xr;
                const f32x4 x1 = *(const f32x4*)(xr + 4);
                bf16x8 af;
                af[0] = (__bf16)x0.x; af[1] = (__bf16)x0.y; af[2] = (__bf16)x0.z; af[3] = (__bf16)x0.w;
                af[4] = (__bf16)x1.x; af[5] = (__bf16)x1.y; af[6] = (__bf16)x1.z; af[7] = (__bf16)x1.w;
                accz[is][0] = __builtin_amdgcn_mfma_f32_16x16x32_bf16(af, tf[0], accz[is][0], 0, 0, 0);
                accz[is][1] = __builtin_amdgcn_mfma_f32_16x16x32_bf16(af, tf[1], accz[is][1], 0, 0, 0);
            }
        }
    }

    float rs[4] = {0.f, 0.f, 0.f, 0.f};
    f32x4 acc[4][2][2];
#pragma unroll
    for (int c = 0; c < 4; ++c)
#pragma unroll
        for (int is = 0; is < 2; ++is)
#pragma unroll
            for (int bs = 0; bs < 2; ++bs) acc[c][is][bs] = (f32x4){0.f, 0.f, 0.f, 0.f};

    const __bf16* Ys = Yt + (size_t)s * 4 * COUTC * NN;

    for (int kk = 0; kk < 32; ++kk) {
        // B-fragments for this step (L2/L3-resident Yt)
        bf16x8 bf[4][2];
        const __bf16* yp = Ys + kk * 32 + quad * 8;
#pragma unroll
        for (int c = 0; c < 4; ++c)
#pragma unroll
            for (int bs = 0; bs < 2; ++bs)
                bf[c][bs] = *(const bf16x8*)(yp + (size_t)(c * COUTC + w * 32 + bs * 16 + m16) * NN);

        const int ib = kk & 1;
        {   // de-interleave channels, convert, stage into buffer ib; fp32 row-sums
            const float v0[4] = {ld[0].x, ld[1].y, ld[2].z, ld[3].w};
            const float v1[4] = {ld[0].y, ld[1].z, ld[2].w, ld[4].x};
            const float v2[4] = {ld[0].z, ld[1].w, ld[3].x, ld[4].y};
            const float v3[4] = {ld[0].w, ld[2].x, ld[3].y, ld[4].z};
            const float* vv[4] = {v0, v1, v2, v3};
#pragma unroll
            for (int c = 0; c < 4; ++c) {
                const float* v = vv[c];
                rs[c] += v[0] + v[1] + v[2] + v[3];
                bf16x4 pk; pk[0] = (__bf16)v[0]; pk[1] = (__bf16)v[1];
                           pk[2] = (__bf16)v[2]; pk[3] = (__bf16)v[3];
                *(bf16x4*)&lA[ib][c][irow][q * 4] = pk;
            }
        }
        __syncthreads();   // staged tile visible; prior-buffer reads are all pre-barrier

        if (kk < 31) {     // prefetch next A step AFTER the barrier drain -> overlaps MFMA
            Ap += 160;
#pragma unroll
            for (int u = 0; u < 5; ++u) ld[u] = __builtin_nontemporal_load((const f32x4*)Ap + u);
        }

#pragma unroll
        for (int c = 0; c < 4; ++c) {
            const bf16x8 af0 = *(const bf16x8*)&lA[ib][c][m16][quad * 8];
            const bf16x8 af1 = *(const bf16x8*)&lA[ib][c][16 + m16][quad * 8];
            acc[c][0][0] = __builtin_amdgcn_mfma_f32_16x16x32_bf16(af0, bf[c][0], acc[c][0][0], 0, 0, 0);
            acc[c][0][1] = __builtin_amdgcn_mfma_f32_16x16x32_bf16(af0, bf[c][1], acc[c][0][1], 0, 0, 0);
            acc[c][1][0] = __builtin_amdgcn_mfma_f32_16x16x32_bf16(af1, bf[c][0], acc[c][1][0], 0, 0, 0);
            acc[c][1][1] = __builtin_amdgcn_mfma_f32_16x16x32_bf16(af1, bf[c][1], acc[c][1][1], 0, 0, 0);
        }
    }

    // row-sums -> norms (8 staging lanes per row, xor-shuffle reduce)
#pragma unroll
    for (int c = 0; c < 4; ++c) {
        float v = rs[c];
        v += __shfl_xor(v, 1);
        v += __shfl_xor(v, 2);
        v += __shfl_xor(v, 4);
        if (q == 0) lnorm[c][irow] = 1.0f / (v + EPSF);
    }
    __syncthreads();

    // epilogue: combine c's with norms, add Z-tile, tanh, NT-store
#pragma unroll
    for (int is = 0; is < 2; ++is) {
        f32x4 nv[4];
#pragma unroll
        for (int c = 0; c < 4; ++c) nv[c] = *(const f32x4*)&lnorm[c][is * 16 + quad * 4];
        const int row0 = i0 + is * 16 + quad * 4;
#pragma unroll
        for (int bs = 0; bs < 2; ++bs) {
            const int b = w * 32 + bs * 16 + m16;
#pragma unroll
            for (int r = 0; r < 4; ++r) {
                float v = acc[0][is][bs][r] * nv[0][r]
                        + acc[1][is][bs][r] * nv[1][r]
                        + acc[2][is][bs][r] * nv[2][r]
                        + acc[3][is][bs][r] * nv[3][r]
                        + accz[is][bs][r];
                const size_t idxo = ((size_t)s * NN + row0 + r) * COUTC + b;
                __builtin_nontemporal_store(tanhf(v), out + idxo);
            }
        }
    }
}

extern "C" void kernel_launch(void* const* d_in, const int* in_sizes, int n_in,
                              void* d_out, int out_size, void* d_ws, size_t ws_size,
                              hipStream_t stream)
{
    const float* A      = (const float*)d_in[0];
    const float* x      = (const float*)d_in[1];
    const float* weight = (const float*)d_in[2];
    const float* theta  = (const float*)d_in[3];
    float* out = (float*)d_out;

    __bf16* Yt = (__bf16*)d_ws;
    __bf16* Wt = (__bf16*)((char*)d_ws + YT_BYTES);

    convert_kernel<<<dim3(320),      dim3(256), 0, stream>>>(weight, theta, Wt);
    prep_kernel   <<<dim3(SS * 4 * 16), dim3(256), 0, stream>>>(x, Wt, Yt);
    main_kernel   <<<dim3(SS * 32),  dim3(256), 0, stream>>>(A, Yt, x, Wt, out);
}